// Round 2
// baseline (417.313 us; speedup 1.0000x reference)
//
#include <hip/hip_runtime.h>

#define BATCH 8
#define SDIM 2048
#define KDIM 2048
#define NDIM 2048
#define BM 128
#define BN 128
#define BK 32
#define KTILES (KDIM / BK)

typedef __bf16 bf16_t;
typedef bf16_t bf16x8 __attribute__((ext_vector_type(8)));
typedef float f32x4 __attribute__((ext_vector_type(4)));
typedef float f32x8 __attribute__((ext_vector_type(8)));

__global__ __launch_bounds__(256, 2)
void bgemm_kernel(const float* __restrict__ A, const float* __restrict__ B,
                  float* __restrict__ O) {
    // LDS tile layout: [k-octet 0..3][row 0..127][k%8] (bf16) — 16B-contiguous
    // per (row, octet): ds_write_b128 staging and ds_read_b128 fragment reads
    // both land stride-16B across lanes -> conflict-free (measured 0 in R1).
    __shared__ alignas(16) bf16_t Asl[2][4 * 128 * 8];
    __shared__ alignas(16) bf16_t Bsl[2][4 * 128 * 8];

    const int tid = threadIdx.x;
    const int gid = blockIdx.x;
    const int batch = gid & 7;         // one batch per XCD
    const int t = gid >> 3;            // 0..255 tile id within batch
    const int bm = (t >> 4) * BM;
    const int bn = (t & 15) * BN;

    float* Ob = O + (size_t)batch * SDIM * NDIM;

    const int lane = tid & 63;
    const int wid = tid >> 6;
    const int wr = wid >> 1;           // wave row 0..1 (64-row half)
    const int wc = wid & 1;            // wave col 0..1 (64-col half)
    const int lr = lane & 15;
    const int lq = lane >> 4;          // k-octet this lane reads

    const int r0 = tid & 127;          // A row / B col staged by this thread
    const int h0 = tid >> 7;           // which 16-wide k-half

    // incremental pointers: advance by BK each K-tile (no per-iter recompute)
    const float* ap = A + (size_t)batch * SDIM * KDIM
                        + (size_t)(bm + r0) * KDIM + h0 * 16;
    const float* bp = B + (size_t)batch * KDIM * NDIM
                        + (size_t)(h0 * 16) * NDIM + bn + r0;

    // raw fp32 staging registers (tile k+1 lives here during compute of k)
    f32x8 fA[2], fB[2];

    auto load_tile = [&]() {
        fA[0] = *reinterpret_cast<const f32x8*>(ap);
        fA[1] = *reinterpret_cast<const f32x8*>(ap + 8);
#pragma unroll
        for (int j = 0; j < 8; ++j) fB[0][j] = bp[(size_t)j * NDIM];
#pragma unroll
        for (int j = 0; j < 8; ++j) fB[1][j] = bp[(size_t)(8 + j) * NDIM];
        ap += BK;
        bp += (size_t)BK * NDIM;
    };

    auto cvt_store = [&](int b) {
#pragma unroll
        for (int o = 0; o < 2; ++o) {
            bf16x8 av = __builtin_convertvector(fA[o], bf16x8);  // v_cvt_pk_bf16_f32
            bf16x8 bv = __builtin_convertvector(fB[o], bf16x8);
            *reinterpret_cast<bf16x8*>(&Asl[b][((h0 * 2 + o) * 128 + r0) * 8]) = av;
            *reinterpret_cast<bf16x8*>(&Bsl[b][((h0 * 2 + o) * 128 + r0) * 8]) = bv;
        }
    };

    f32x4 acc[4][4];
#pragma unroll
    for (int m = 0; m < 4; ++m)
#pragma unroll
        for (int n = 0; n < 4; ++n)
            acc[m][n] = (f32x4){0.f, 0.f, 0.f, 0.f};

    // prologue: tile0 -> LDS[0]; tile1 loads in flight
    load_tile();
    cvt_store(0);
    load_tile();
    __syncthreads();

    int buf = 0;
    for (int kt = 0; kt < KTILES; ++kt) {
        bf16x8 af[4], bfv[4];
#pragma unroll
        for (int m = 0; m < 4; ++m)
            af[m] = *reinterpret_cast<const bf16x8*>(
                &Asl[buf][(lq * 128 + wr * 64 + m * 16 + lr) * 8]);
#pragma unroll
        for (int n = 0; n < 4; ++n)
            bfv[n] = *reinterpret_cast<const bf16x8*>(
                &Bsl[buf][(lq * 128 + wc * 64 + n * 16 + lr) * 8]);
#pragma unroll
        for (int m = 0; m < 4; ++m)
#pragma unroll
            for (int n = 0; n < 4; ++n)
                acc[m][n] = __builtin_amdgcn_mfma_f32_16x16x32_bf16(
                    af[m], bfv[n], acc[m][n], 0, 0, 0);
        if (kt + 1 < KTILES) {
            cvt_store(buf ^ 1);            // tile kt+1 (vmcnt waits loads from a full iter ago)
            if (kt + 2 < KTILES) load_tile();  // issue tile kt+2
        }
        __syncthreads();
        buf ^= 1;
    }

    // epilogue: C/D layout col=lane&15, row=(lane>>4)*4+reg
#pragma unroll
    for (int m = 0; m < 4; ++m) {
        const int row0 = bm + wr * 64 + m * 16 + lq * 4;
#pragma unroll
        for (int n = 0; n < 4; ++n) {
            const int col = bn + wc * 64 + n * 16 + lr;
#pragma unroll
            for (int j = 0; j < 4; ++j)
                Ob[(size_t)(row0 + j) * NDIM + col] = acc[m][n][j];
        }
    }
}

extern "C" void kernel_launch(void* const* d_in, const int* in_sizes, int n_in,
                              void* d_out, int out_size, void* d_ws, size_t ws_size,
                              hipStream_t stream) {
    const float* a = (const float*)d_in[0];
    const float* b = (const float*)d_in[1];
    float* o = (float*)d_out;
    dim3 grid(BATCH * (SDIM / BM) * (NDIM / BN));  // 2048
    dim3 block(256);
    hipLaunchKernelGGL(bgemm_kernel, grid, block, 0, stream, a, b, o);
}